// Round 6
// baseline (5315.768 us; speedup 1.0000x reference)
//
#include <hip/hip_runtime.h>
#include <float.h>

// VectorQuantizer on MI355X — bit-exact numpy-f32 replication (R4-proven numerics),
// restructured for operand locality:
//   R5 post-mortem: VGPR=60 (<64) -> compiler rematerialized xv from global inside
//   the k-loop; SGPR=32 -> e-rows not scalar-promoted. Inner loop was VMEM-latency
//   bound (VALUBusy 25% at 47% occupancy).
//   R6: (1) xv[64] pinned in VGPRs via identity asm launder; (2) e staged through
//   double-buffered LDS (1 float4/thread/chunk, store-after-compute hides latency);
//   (3) uniform ds_read_b128 broadcasts feed the fma chains. Arithmetic order
//   unchanged -> bit-identical idx.
#pragma clang fp contract(off)

#define K_EMB   512
#define D_EMB   64
#define Q_ELEMS 4194304   // 64 * 64 * 32 * 32
#define CHUNK   16        // codes per LDS chunk (16*64 floats = 4 KB = 256 float4)
#define NCHUNK  32        // 512 / 16

// numpy pairwise_sum order for n=64 contiguous f32, summing PRE-ROUNDED squares.
__device__ __forceinline__ float np_sumsq64(const float* __restrict__ v) {
    float r[8];
    #pragma unroll
    for (int j = 0; j < 8; ++j) r[j] = v[j] * v[j];
    #pragma unroll
    for (int i = 8; i < 64; i += 8) {
        #pragma unroll
        for (int j = 0; j < 8; ++j) {
            float s = v[i + j] * v[i + j];
            r[j] = r[j] + s;
        }
    }
    return ((r[0] + r[1]) + (r[2] + r[3])) + ((r[4] + r[5]) + (r[6] + r[7]));
}

// ---------------- kernel 1: t2[k] = np-f32 sum(emb_k^2) ----------------
__global__ __launch_bounds__(256) void vq_prep(const float* __restrict__ emb,
                                               float* __restrict__ t2) {
    int k = blockIdx.x * 256 + threadIdx.x;
    if (k < K_EMB) {
        float e[D_EMB];
        const float* ep = emb + (k << 6);
        #pragma unroll
        for (int j = 0; j < D_EMB; ++j) e[j] = ep[j];
        t2[k] = np_sumsq64(e);
    }
}

// ---------------- kernel 2: main VQ ----------------
__global__ __launch_bounds__(256, 4) void vq_main(const float* __restrict__ x,
                                                  const float* __restrict__ emb,
                                                  const float* __restrict__ t2,
                                                  float* __restrict__ out_q,
                                                  float* __restrict__ out_idx,
                                                  float* __restrict__ partial) {
    const int tid = threadIdx.x;
    const int n   = blockIdx.x * 256 + tid;          // pixel index (thread-owned)
    const int b   = n >> 10;
    const int hw  = n & 1023;
    const float* __restrict__ xp = x + b * 65536 + hw;

    __shared__ __align__(16) float ebuf[2][CHUNK * D_EMB];  // 2 x 4 KB
    __shared__ float t2s[K_EMB];                            // 2 KB
    const float4* __restrict__ emb4 = (const float4*)emb;

    // prologue: stage chunk 0 + t2 into LDS
    {
        float4 p0 = emb4[tid];                     // chunk 0, slot tid
        ((float4*)ebuf[0])[tid] = p0;
        t2s[tid]       = t2[tid];
        t2s[tid + 256] = t2[tid + 256];
    }

    // x[n, 0..63] into registers (coalesced per-d across lanes), pinned via asm
    float xv[D_EMB];
    #pragma unroll
    for (int d = 0; d < D_EMB; ++d) xv[d] = xp[d * 1024];
    #pragma unroll
    for (int d = 0; d < D_EMB; ++d) asm volatile("" : "+v"(xv[d]));

    const float t1 = np_sumsq64(xv);   // numpy tree, f32

    __syncthreads();   // chunk 0 + t2 staged

    float best = FLT_MAX;
    int   bi   = 0;

    for (int c = 0; c < NCHUNK; ++c) {
        const int cur = c & 1;
        // issue next chunk's global load early (latency hides under compute)
        float4 pre;
        if (c + 1 < NCHUNK) pre = emb4[(c + 1) * 256 + tid];

        const float* eb = ebuf[cur];
        #pragma unroll
        for (int kk = 0; kk < CHUNK; kk += 4) {
            const int k = c * CHUNK + kk;
            const float4* E0 = (const float4*)(eb + (kk + 0) * D_EMB);
            const float4* E1 = (const float4*)(eb + (kk + 1) * D_EMB);
            const float4* E2 = (const float4*)(eb + (kk + 2) * D_EMB);
            const float4* E3 = (const float4*)(eb + (kk + 3) * D_EMB);
            float a0 = 0.f, a1 = 0.f, a2 = 0.f, a3 = 0.f;
            #pragma unroll
            for (int j = 0; j < 16; ++j) {
                float4 v0 = E0[j], v1 = E1[j], v2 = E2[j], v3 = E3[j];
                const int d = j * 4;
                // sequential-d fma chain per code (BLAS order, one rounding/step)
                a0 = fmaf(xv[d + 0], v0.x, a0);
                a0 = fmaf(xv[d + 1], v0.y, a0);
                a0 = fmaf(xv[d + 2], v0.z, a0);
                a0 = fmaf(xv[d + 3], v0.w, a0);
                a1 = fmaf(xv[d + 0], v1.x, a1);
                a1 = fmaf(xv[d + 1], v1.y, a1);
                a1 = fmaf(xv[d + 2], v1.z, a1);
                a1 = fmaf(xv[d + 3], v1.w, a1);
                a2 = fmaf(xv[d + 0], v2.x, a2);
                a2 = fmaf(xv[d + 1], v2.y, a2);
                a2 = fmaf(xv[d + 2], v2.z, a2);
                a2 = fmaf(xv[d + 3], v2.w, a2);
                a3 = fmaf(xv[d + 0], v3.x, a3);
                a3 = fmaf(xv[d + 1], v3.y, a3);
                a3 = fmaf(xv[d + 2], v3.z, a3);
                a3 = fmaf(xv[d + 3], v3.w, a3);
            }
            // dist = fl32( fl32(t1+t2) - 2*d ): 2*d exact -> fmaf = same rounding
            float X0 = t1 + t2s[k + 0];
            float X1 = t1 + t2s[k + 1];
            float X2 = t1 + t2s[k + 2];
            float X3 = t1 + t2s[k + 3];
            float d0 = fmaf(-2.f, a0, X0);
            float d1 = fmaf(-2.f, a1, X1);
            float d2 = fmaf(-2.f, a2, X2);
            float d3 = fmaf(-2.f, a3, X3);
            if (d0 < best) { best = d0; bi = k + 0; }   // strict <, ascending k
            if (d1 < best) { best = d1; bi = k + 1; }
            if (d2 < best) { best = d2; bi = k + 2; }
            if (d3 < best) { best = d3; bi = k + 3; }
        }

        if (c + 1 < NCHUNK) {
            // safe without pre-store sync: all waves are past compute(c-1) (trailing
            // barrier of iter c-1), and this write targets buf[cur^1] (chunk c-1).
            ((float4*)ebuf[cur ^ 1])[tid] = pre;
            __syncthreads();
        }
    }

    // epilogue: gather winning embedding, write quantized, loss partial
    const float4* __restrict__ eq = (const float4*)(emb + (bi << 6));
    float* __restrict__ qp = out_q + b * 65536 + hw;
    float acc = 0.f;
    #pragma unroll
    for (int j = 0; j < 16; ++j) {
        float4 q = eq[j];
        const int d = j * 4;
        float f0 = q.x - xv[d + 0];
        float f1 = q.y - xv[d + 1];
        float f2 = q.z - xv[d + 2];
        float f3 = q.w - xv[d + 3];
        acc = fmaf(f0, f0, acc);
        acc = fmaf(f1, f1, acc);
        acc = fmaf(f2, f2, acc);
        acc = fmaf(f3, f3, acc);
        qp[(d + 0) * 1024] = q.x;
        qp[(d + 1) * 1024] = q.y;
        qp[(d + 2) * 1024] = q.z;
        qp[(d + 3) * 1024] = q.w;
    }
    out_idx[n] = (float)bi;

    // block loss partial: wave shuffle reduce, then LDS across 4 waves
    #pragma unroll
    for (int off = 32; off > 0; off >>= 1) acc += __shfl_down(acc, off);
    __shared__ float red[4];
    if ((tid & 63) == 0) red[tid >> 6] = acc;
    __syncthreads();
    if (tid == 0)
        partial[blockIdx.x] = (red[0] + red[1]) + (red[2] + red[3]);
}

// ---------------- kernel 3: finalize loss over 256 partials ----------------
__global__ __launch_bounds__(256) void vq_loss(const float* __restrict__ partial,
                                               float* __restrict__ loss) {
    float v = partial[threadIdx.x];
    #pragma unroll
    for (int off = 32; off > 0; off >>= 1) v += __shfl_down(v, off);
    __shared__ float red[4];
    if ((threadIdx.x & 63) == 0) red[threadIdx.x >> 6] = v;
    __syncthreads();
    if (threadIdx.x == 0)
        loss[0] = 1.25f * ((red[0] + red[1]) + (red[2] + red[3])) / (float)Q_ELEMS;
}

extern "C" void kernel_launch(void* const* d_in, const int* in_sizes, int n_in,
                              void* d_out, int out_size, void* d_ws, size_t ws_size,
                              hipStream_t stream) {
    const float* x   = (const float*)d_in[0];   // [64,64,32,32] NCHW
    const float* emb = (const float*)d_in[1];   // [512,64]

    float* out_q    = (float*)d_out;                // [4194304]
    float* out_loss = (float*)d_out + Q_ELEMS;      // [1]
    float* out_idx  = (float*)d_out + Q_ELEMS + 1;  // [65536] as float

    float* t2      = (float*)d_ws;       // 512 floats
    float* partial = t2 + K_EMB;         // 256 floats

    vq_prep<<<2, 256, 0, stream>>>(emb, t2);
    vq_main<<<256, 256, 0, stream>>>(x, emb, t2, out_q, out_idx, partial);
    vq_loss<<<1, 256, 0, stream>>>(partial, out_loss);
}

// Round 7
// 93.050 us; speedup vs baseline: 57.1280x; 57.1280x over previous
//
#include <hip/hip_runtime.h>
#include <float.h>

// VectorQuantizer on MI355X — bit-exact numpy-f32 replication (R4-proven numerics).
//
// R7 = R4's codegen at R5's occupancy:
//   R4 (SGPR=112): compiler scalar-promoted e-rows to s_load -> inner loop was
//     v_fmac(v,s,v); only 1 wave/SIMD -> VALUBusy 22%.
//   R5 (SGPR=32): promotion lost because wave = tid>>6 is not PROVABLY uniform;
//     e-loads became vector VMEM -> latency-bound 25% despite 4 waves/SIMD.
//   R6: asm-pinning xv under a 64-VGPR allocator target forced scratch spills
//     (12 GB traffic, 5.5 ms). Reverted.
//   R7: (1) wave via readfirstlane -> uniform e-addresses -> s_load promotion;
//       (2) __launch_bounds__(256,2) -> 256-VGPR headroom, xv stays live, no
//           remat/spill; (3) e read directly from global (no LDS staging).
#pragma clang fp contract(off)

#define K_EMB   512
#define D_EMB   64
#define Q_ELEMS 4194304   // 64 * 64 * 32 * 32
#define NBLK    1024      // vq_main grid: 64 pixels per block, 4 waves split K

// numpy pairwise_sum order for n=64 contiguous f32, summing PRE-ROUNDED squares.
__device__ __forceinline__ float np_sumsq64(const float* __restrict__ v) {
    float r[8];
    #pragma unroll
    for (int j = 0; j < 8; ++j) r[j] = v[j] * v[j];
    #pragma unroll
    for (int i = 8; i < 64; i += 8) {
        #pragma unroll
        for (int j = 0; j < 8; ++j) {
            float s = v[i + j] * v[i + j];
            r[j] = r[j] + s;
        }
    }
    return ((r[0] + r[1]) + (r[2] + r[3])) + ((r[4] + r[5]) + (r[6] + r[7]));
}

// ---------------- kernel 1: t2[k] = np-f32 sum(emb_k^2) ----------------
__global__ __launch_bounds__(256) void vq_prep(const float* __restrict__ emb,
                                               float* __restrict__ t2) {
    int k = blockIdx.x * 256 + threadIdx.x;
    if (k < K_EMB) {
        float e[D_EMB];
        const float* ep = emb + (k << 6);
        #pragma unroll
        for (int j = 0; j < D_EMB; ++j) e[j] = ep[j];
        t2[k] = np_sumsq64(e);
    }
}

// ---------------- kernel 2: main VQ ----------------
__global__ __launch_bounds__(256, 2) void vq_main(const float* __restrict__ x,
                                                  const float* __restrict__ emb,
                                                  const float* __restrict__ t2,
                                                  float* __restrict__ out_q,
                                                  float* __restrict__ out_idx,
                                                  float* __restrict__ partial) {
    const int tid  = threadIdx.x;
    const int lane = tid & 63;
    // PROVABLY wave-uniform wave id -> e addresses become scalar -> s_load
    const int wave = __builtin_amdgcn_readfirstlane(tid >> 6);

    const int n  = blockIdx.x * 64 + lane;           // pixel index
    const int b  = n >> 10;
    const int hw = n & 1023;
    const float* __restrict__ xp = x + b * 65536 + hw;

    // x[n, 0..63] into registers (coalesced: consecutive lanes -> consecutive hw)
    float xv[D_EMB];
    #pragma unroll
    for (int d = 0; d < D_EMB; ++d) xv[d] = xp[d * 1024];

    const float t1 = np_sumsq64(xv);   // numpy tree, f32

    float best = FLT_MAX;
    int   bi   = 0;
    const int k0 = wave << 7;          // this wave's 128-code range (uniform)
    for (int kk = 0; kk < 128; kk += 4) {
        const int k = k0 + kk;
        const float* __restrict__ e0 = emb + ((k + 0) << 6);  // uniform -> s_load
        const float* __restrict__ e1 = emb + ((k + 1) << 6);
        const float* __restrict__ e2 = emb + ((k + 2) << 6);
        const float* __restrict__ e3 = emb + ((k + 3) << 6);
        float a0 = 0.f, a1 = 0.f, a2 = 0.f, a3 = 0.f;
        #pragma unroll
        for (int d = 0; d < D_EMB; ++d) {
            a0 = fmaf(xv[d], e0[d], a0);   // BLAS chain: one fma rounding per step
            a1 = fmaf(xv[d], e1[d], a1);
            a2 = fmaf(xv[d], e2[d], a2);
            a3 = fmaf(xv[d], e3[d], a3);
        }
        // dist = fl32( fl32(t1+t2) - 2*d ): 2*d exact -> fmaf = identical rounding
        float X0 = t1 + t2[k + 0];
        float X1 = t1 + t2[k + 1];
        float X2 = t1 + t2[k + 2];
        float X3 = t1 + t2[k + 3];
        float d0 = fmaf(-2.f, a0, X0);
        float d1 = fmaf(-2.f, a1, X1);
        float d2 = fmaf(-2.f, a2, X2);
        float d3 = fmaf(-2.f, a3, X3);
        if (d0 < best) { best = d0; bi = k + 0; }   // strict <: first-min tiebreak
        if (d1 < best) { best = d1; bi = k + 1; }
        if (d2 < best) { best = d2; bi = k + 2; }
        if (d3 < best) { best = d3; bi = k + 3; }
    }

    // cross-wave argmin merge (ascending wave == ascending k; strict <)
    __shared__ float s_best[4][64];
    __shared__ int   s_bi[4][64];
    s_best[wave][lane] = best;
    s_bi[wave][lane]   = bi;
    __syncthreads();
    if (wave != 0) return;

    #pragma unroll
    for (int w = 1; w < 4; ++w) {
        float dw = s_best[w][lane];
        if (dw < best) { best = dw; bi = s_bi[w][lane]; }
    }

    // epilogue (wave 0): gather winning embedding, write quantized, loss partial
    const float4* __restrict__ eq = (const float4*)(emb + (bi << 6));
    float* __restrict__ qp = out_q + b * 65536 + hw;
    float acc = 0.f;
    #pragma unroll
    for (int j = 0; j < 16; ++j) {
        float4 q = eq[j];
        const int d = j * 4;
        float f0 = q.x - xv[d + 0];
        float f1 = q.y - xv[d + 1];
        float f2 = q.z - xv[d + 2];
        float f3 = q.w - xv[d + 3];
        acc = fmaf(f0, f0, acc);
        acc = fmaf(f1, f1, acc);
        acc = fmaf(f2, f2, acc);
        acc = fmaf(f3, f3, acc);
        qp[(d + 0) * 1024] = q.x;
        qp[(d + 1) * 1024] = q.y;
        qp[(d + 2) * 1024] = q.z;
        qp[(d + 3) * 1024] = q.w;
    }
    out_idx[n] = (float)bi;

    // wave-internal loss reduce (single wave -> no LDS needed)
    #pragma unroll
    for (int off = 32; off > 0; off >>= 1) acc += __shfl_down(acc, off);
    if (lane == 0) partial[blockIdx.x] = acc;
}

// ---------------- kernel 3: finalize loss over 1024 partials ----------------
__global__ __launch_bounds__(256) void vq_loss(const float* __restrict__ partial,
                                               float* __restrict__ loss) {
    const int t = threadIdx.x;
    float v = (partial[t] + partial[t + 256]) + (partial[t + 512] + partial[t + 768]);
    #pragma unroll
    for (int off = 32; off > 0; off >>= 1) v += __shfl_down(v, off);
    __shared__ float red[4];
    if ((t & 63) == 0) red[t >> 6] = v;
    __syncthreads();
    if (t == 0)
        loss[0] = 1.25f * ((red[0] + red[1]) + (red[2] + red[3])) / (float)Q_ELEMS;
}

extern "C" void kernel_launch(void* const* d_in, const int* in_sizes, int n_in,
                              void* d_out, int out_size, void* d_ws, size_t ws_size,
                              hipStream_t stream) {
    const float* x   = (const float*)d_in[0];   // [64,64,32,32] NCHW
    const float* emb = (const float*)d_in[1];   // [512,64]

    float* out_q    = (float*)d_out;                // [4194304]
    float* out_loss = (float*)d_out + Q_ELEMS;      // [1]
    float* out_idx  = (float*)d_out + Q_ELEMS + 1;  // [65536] as float

    float* t2      = (float*)d_ws;       // 512 floats
    float* partial = t2 + K_EMB;         // 1024 floats

    vq_prep<<<2, 256, 0, stream>>>(emb, t2);
    vq_main<<<NBLK, 256, 0, stream>>>(x, emb, t2, out_q, out_idx, partial);
    vq_loss<<<1, 256, 0, stream>>>(partial, out_loss);
}

// Round 8
// 92.472 us; speedup vs baseline: 57.4853x; 1.0063x over previous
//
#include <hip/hip_runtime.h>
#include <float.h>

// VectorQuantizer on MI355X — bit-exact numpy-f32 replication (R4-proven numerics).
//
// Ladder: R4 274us (s_load promotion, 1 wave/SIMD) -> R7 97us (readfirstlane
// restores promotion at 4 waves/SIMD, VALUBusy 63%).
// R7 post-mortem: VGPR=56 — the allocator targets the 8-waves/EU tier (<=64 VGPR)
// and rematerializes xv[64] from memory inside the k-loop; the reload address
// arithmetic is ~half of all VALU cycles (VALU time 60us vs 27us fma floor).
// launch_bounds' 2nd arg is only a FLOOR on waves/EU; the allocator still
// squeezes. R6 showed pinning under that heuristic causes scratch spills.
//
// R8: amdgpu_waves_per_eu(4,4) — pin the allocator's occupancy TARGET at 4
// waves/EU (128-VGPR budget). xv[64] stays register-resident with no asm pin.
#pragma clang fp contract(off)

#define K_EMB   512
#define D_EMB   64
#define Q_ELEMS 4194304   // 64 * 64 * 32 * 32
#define NBLK    1024      // vq_main grid: 64 pixels per block, 4 waves split K

// numpy pairwise_sum order for n=64 contiguous f32, summing PRE-ROUNDED squares.
__device__ __forceinline__ float np_sumsq64(const float* __restrict__ v) {
    float r[8];
    #pragma unroll
    for (int j = 0; j < 8; ++j) r[j] = v[j] * v[j];
    #pragma unroll
    for (int i = 8; i < 64; i += 8) {
        #pragma unroll
        for (int j = 0; j < 8; ++j) {
            float s = v[i + j] * v[i + j];
            r[j] = r[j] + s;
        }
    }
    return ((r[0] + r[1]) + (r[2] + r[3])) + ((r[4] + r[5]) + (r[6] + r[7]));
}

// ---------------- kernel 1: t2[k] = np-f32 sum(emb_k^2) ----------------
__global__ __launch_bounds__(256) void vq_prep(const float* __restrict__ emb,
                                               float* __restrict__ t2) {
    int k = blockIdx.x * 256 + threadIdx.x;
    if (k < K_EMB) {
        float e[D_EMB];
        const float* ep = emb + (k << 6);
        #pragma unroll
        for (int j = 0; j < D_EMB; ++j) e[j] = ep[j];
        t2[k] = np_sumsq64(e);
    }
}

// ---------------- kernel 2: main VQ ----------------
__global__ __launch_bounds__(256)
__attribute__((amdgpu_waves_per_eu(4, 4)))
void vq_main(const float* __restrict__ x,
             const float* __restrict__ emb,
             const float* __restrict__ t2,
             float* __restrict__ out_q,
             float* __restrict__ out_idx,
             float* __restrict__ partial) {
    const int tid  = threadIdx.x;
    const int lane = tid & 63;
    // PROVABLY wave-uniform wave id -> e addresses become scalar -> s_load
    const int wave = __builtin_amdgcn_readfirstlane(tid >> 6);

    const int n  = blockIdx.x * 64 + lane;           // pixel index
    const int b  = n >> 10;
    const int hw = n & 1023;
    const float* __restrict__ xp = x + b * 65536 + hw;

    // x[n, 0..63] into registers (coalesced: consecutive lanes -> consecutive hw)
    float xv[D_EMB];
    #pragma unroll
    for (int d = 0; d < D_EMB; ++d) xv[d] = xp[d * 1024];

    const float t1 = np_sumsq64(xv);   // numpy tree, f32

    float best = FLT_MAX;
    int   bi   = 0;
    const int k0 = wave << 7;          // this wave's 128-code range (uniform)
    for (int kk = 0; kk < 128; kk += 4) {
        const int k = k0 + kk;
        const float* __restrict__ e0 = emb + ((k + 0) << 6);  // uniform -> s_load
        const float* __restrict__ e1 = emb + ((k + 1) << 6);
        const float* __restrict__ e2 = emb + ((k + 2) << 6);
        const float* __restrict__ e3 = emb + ((k + 3) << 6);
        float a0 = 0.f, a1 = 0.f, a2 = 0.f, a3 = 0.f;
        #pragma unroll
        for (int d = 0; d < D_EMB; ++d) {
            a0 = fmaf(xv[d], e0[d], a0);   // BLAS chain: one fma rounding per step
            a1 = fmaf(xv[d], e1[d], a1);
            a2 = fmaf(xv[d], e2[d], a2);
            a3 = fmaf(xv[d], e3[d], a3);
        }
        // dist = fl32( fl32(t1+t2) - 2*d ): 2*d exact -> fmaf = identical rounding
        float X0 = t1 + t2[k + 0];
        float X1 = t1 + t2[k + 1];
        float X2 = t1 + t2[k + 2];
        float X3 = t1 + t2[k + 3];
        float d0 = fmaf(-2.f, a0, X0);
        float d1 = fmaf(-2.f, a1, X1);
        float d2 = fmaf(-2.f, a2, X2);
        float d3 = fmaf(-2.f, a3, X3);
        if (d0 < best) { best = d0; bi = k + 0; }   // strict <: first-min tiebreak
        if (d1 < best) { best = d1; bi = k + 1; }
        if (d2 < best) { best = d2; bi = k + 2; }
        if (d3 < best) { best = d3; bi = k + 3; }
    }

    // cross-wave argmin merge (ascending wave == ascending k; strict <)
    __shared__ float s_best[4][64];
    __shared__ int   s_bi[4][64];
    s_best[wave][lane] = best;
    s_bi[wave][lane]   = bi;
    __syncthreads();
    if (wave != 0) return;

    #pragma unroll
    for (int w = 1; w < 4; ++w) {
        float dw = s_best[w][lane];
        if (dw < best) { best = dw; bi = s_bi[w][lane]; }
    }

    // epilogue (wave 0): gather winning embedding, write quantized, loss partial
    const float4* __restrict__ eq = (const float4*)(emb + (bi << 6));
    float* __restrict__ qp = out_q + b * 65536 + hw;
    float acc = 0.f;
    #pragma unroll
    for (int j = 0; j < 16; ++j) {
        float4 q = eq[j];
        const int d = j * 4;
        float f0 = q.x - xv[d + 0];
        float f1 = q.y - xv[d + 1];
        float f2 = q.z - xv[d + 2];
        float f3 = q.w - xv[d + 3];
        acc = fmaf(f0, f0, acc);
        acc = fmaf(f1, f1, acc);
        acc = fmaf(f2, f2, acc);
        acc = fmaf(f3, f3, acc);
        qp[(d + 0) * 1024] = q.x;
        qp[(d + 1) * 1024] = q.y;
        qp[(d + 2) * 1024] = q.z;
        qp[(d + 3) * 1024] = q.w;
    }
    out_idx[n] = (float)bi;

    // wave-internal loss reduce (single wave -> no LDS needed)
    #pragma unroll
    for (int off = 32; off > 0; off >>= 1) acc += __shfl_down(acc, off);
    if (lane == 0) partial[blockIdx.x] = acc;
}

// ---------------- kernel 3: finalize loss over 1024 partials ----------------
__global__ __launch_bounds__(256) void vq_loss(const float* __restrict__ partial,
                                               float* __restrict__ loss) {
    const int t = threadIdx.x;
    float v = (partial[t] + partial[t + 256]) + (partial[t + 512] + partial[t + 768]);
    #pragma unroll
    for (int off = 32; off > 0; off >>= 1) v += __shfl_down(v, off);
    __shared__ float red[4];
    if ((t & 63) == 0) red[t >> 6] = v;
    __syncthreads();
    if (t == 0)
        loss[0] = 1.25f * ((red[0] + red[1]) + (red[2] + red[3])) / (float)Q_ELEMS;
}

extern "C" void kernel_launch(void* const* d_in, const int* in_sizes, int n_in,
                              void* d_out, int out_size, void* d_ws, size_t ws_size,
                              hipStream_t stream) {
    const float* x   = (const float*)d_in[0];   // [64,64,32,32] NCHW
    const float* emb = (const float*)d_in[1];   // [512,64]

    float* out_q    = (float*)d_out;                // [4194304]
    float* out_loss = (float*)d_out + Q_ELEMS;      // [1]
    float* out_idx  = (float*)d_out + Q_ELEMS + 1;  // [65536] as float

    float* t2      = (float*)d_ws;       // 512 floats
    float* partial = t2 + K_EMB;         // 1024 floats

    vq_prep<<<2, 256, 0, stream>>>(emb, t2);
    vq_main<<<NBLK, 256, 0, stream>>>(x, emb, t2, out_q, out_idx, partial);
    vq_loss<<<1, 256, 0, stream>>>(partial, out_loss);
}